// Round 1
// baseline (10763.280 us; speedup 1.0000x reference)
//
#include <hip/hip_runtime.h>
#include <math.h>

namespace {

constexpr int kB = 256;
constexpr int kT = 128;
constexpr int kFC = 128;
constexpr int kUNIT = 256;
constexpr int kNACT = 82;
constexpr int kWDIM = 300;
constexpr int kPOS = 50;

__device__ __forceinline__ float sigf(float x) { return 1.0f / (1.0f + expf(-x)); }

template <int ROWS>
__device__ __forceinline__ void ldsvec(const float* p, float* v) {
  if constexpr (ROWS == 4) {
    float4 t = *reinterpret_cast<const float4*>(p);
    v[0] = t.x; v[1] = t.y; v[2] = t.z; v[3] = t.w;
  } else {
    float2 t = *reinterpret_cast<const float2*>(p);
    v[0] = t.x; v[1] = t.y;
  }
}

template <int ROWS>
__device__ __forceinline__ void stsvec(float* p, const float* v) {
  if constexpr (ROWS == 4) {
    *reinterpret_cast<float4*>(p) = make_float4(v[0], v[1], v[2], v[3]);
  } else {
    *reinterpret_cast<float2*>(p) = make_float2(v[0], v[1]);
  }
}

// ---------------------------------------------------------------------------
// Reorder LSTM weight (K,1024) row-major -> Wr[k][u][g] = W[k][g*256+u]
// so one float4 load per k gives all 4 gates for column u.
// ---------------------------------------------------------------------------
__global__ void reorder_w_kernel(const float* __restrict__ W, float* __restrict__ Wr, int K) {
  int idx = blockIdx.x * 256 + threadIdx.x;
  int total = K * 1024;
  if (idx < total) {
    int k = idx >> 10;
    int c = idx & 1023;
    int u = c >> 2;
    int g = c & 3;
    Wr[idx] = W[k * 1024 + g * 256 + u];
  }
}

// ---------------------------------------------------------------------------
// Embeddings: relu(concat(W_word[wid], W_pos[pid]) @ emb_W + emb_b)
// 8 (b,t) pairs per block, 128 threads = output columns.
// ---------------------------------------------------------------------------
__global__ __launch_bounds__(128) void emb_kernel(
    const int* __restrict__ twid, const int* __restrict__ tpid,
    const int* __restrict__ bwid, const int* __restrict__ bpid,
    const float* __restrict__ W_word, const float* __restrict__ W_pos,
    const float* __restrict__ emb_W, const float* __restrict__ emb_b,
    float* __restrict__ tree_emb, float* __restrict__ buff_emb) {
  __shared__ float xs[8][352];
  const int tid = threadIdx.x;
  const int pair0 = blockIdx.x * 8;
  const int NTREE = kB * kT;

  for (int p = 0; p < 8; ++p) {
    int P = pair0 + p;
    bool isTree = P < NTREE;
    int idx = isTree ? P : P - NTREE;
    int wid = isTree ? twid[idx] : bwid[idx];
    int pid = isTree ? tpid[idx] : bpid[idx];
    const float* wrow = W_word + (size_t)wid * kWDIM;
    for (int k = tid; k < kWDIM; k += 128) xs[p][k] = wrow[k];
    if (tid < kPOS) xs[p][kWDIM + tid] = W_pos[pid * kPOS + tid];
  }
  __syncthreads();

  float acc[8];
  const float bj = emb_b[tid];
#pragma unroll
  for (int p = 0; p < 8; ++p) acc[p] = bj;

#pragma unroll 10
  for (int k = 0; k < kWDIM + kPOS; ++k) {
    float w = emb_W[k * kFC + tid];
#pragma unroll
    for (int p = 0; p < 8; ++p) acc[p] = fmaf(xs[p][k], w, acc[p]);
  }

  for (int p = 0; p < 8; ++p) {
    int P = pair0 + p;
    bool isTree = P < NTREE;
    int idx = isTree ? P : P - NTREE;
    float v = fmaxf(acc[p], 0.0f);
    (isTree ? tree_emb : buff_emb)[(size_t)idx * kFC + tid] = v;
  }
}

// ---------------------------------------------------------------------------
// Tree composition scan: one block per batch row, res[128][128] fully in LDS.
// Sequential over i=1..127; leaf steps skip the GEMM entirely (block-uniform).
// ---------------------------------------------------------------------------
__global__ __launch_bounds__(128) void tree_scan_kernel(
    const float* __restrict__ tree_emb,
    const int* __restrict__ head_ord, const int* __restrict__ dep_ord,
    const int* __restrict__ rel_id, const int* __restrict__ is_leaf,
    const float* __restrict__ W_rel,
    const float* __restrict__ rec_W, const float* __restrict__ rec_b,
    float* __restrict__ res_g) {
  __shared__ float res[kT][kFC];  // exactly 64 KB
  const int b = blockIdx.x;
  const int j = threadIdx.x;

  res[0][j] = tree_emb[((size_t)b * kT) * kFC + j];
  const float rb = rec_b[j];
  __syncthreads();

  for (int i = 1; i < kT; ++i) {
    const int base = b * kT + i;
    const int leaf = is_leaf[base];  // uniform across block
    if (leaf > 0) {
      res[i][j] = tree_emb[(size_t)base * kFC + j];
    } else {
      const int hi = head_ord[base];
      const int di = dep_ord[base];
      const int rid = rel_id[base];
      float acc = rb;
#pragma unroll 8
      for (int k = 0; k < 128; ++k)
        acc = fmaf(res[hi][k], rec_W[k * kFC + j], acc);
#pragma unroll 5
      for (int k = 0; k < 50; ++k)
        acc = fmaf(W_rel[rid * 50 + k], rec_W[(128 + k) * kFC + j], acc);
#pragma unroll 8
      for (int k = 0; k < 128; ++k)
        acc = fmaf(res[di][k], rec_W[(178 + k) * kFC + j], acc);
      res[i][j] = tanhf(acc);
    }
    __syncthreads();
  }

  for (int idx = j; idx < kT * kFC; idx += 128) {
    int t = idx >> 7;
    int jj = idx & 127;
    res_g[((size_t)b * kT + t) * kFC + jj] = res[t][jj];
  }
}

// ---------------------------------------------------------------------------
// 2-layer LSTM, batch-split: ROWS batch rows per block, 256 threads = h cols.
// h kept in LDS (transposed [k][r]), c in registers. Gate-interleaved weights.
// MODE 0: stack (gather res_g via stack_order); 1: buff; 2: act (gather W_act).
// ---------------------------------------------------------------------------
template <int ROWS, int D, int STEPS, int MODE>
__device__ __forceinline__ void lstm_body(
    int blk, float* smem,
    const float* __restrict__ xsrc, const int* __restrict__ order,
    const int* __restrict__ lengths,
    const float* __restrict__ W1r, const float* __restrict__ b1,
    const float* __restrict__ W2r, const float* __restrict__ b2,
    float* __restrict__ hcat, int hoff) {
  float* xs  = smem;                    // D*ROWS
  float* h1s = xs + D * ROWS;           // 256*ROWS
  float* x2s = h1s + kUNIT * ROWS;      // 256*ROWS
  float* h2s = x2s + kUNIT * ROWS;      // 256*ROWS

  const int u = threadIdx.x;
  const int row0 = blk * ROWS;

  float c1[ROWS], c2[ROWS], h1reg[ROWS], h2reg[ROWS];
  int len[ROWS];
  int tmax = 0;
#pragma unroll
  for (int r = 0; r < ROWS; ++r) {
    c1[r] = 0.f; c2[r] = 0.f; h1reg[r] = 0.f; h2reg[r] = 0.f;
    len[r] = lengths[row0 + r];
    tmax = len[r] > tmax ? len[r] : tmax;
  }
#pragma unroll
  for (int r = 0; r < ROWS; ++r) { h1s[u * ROWS + r] = 0.f; h2s[u * ROWS + r] = 0.f; }

  float bi1[4], bi2[4];
#pragma unroll
  for (int g = 0; g < 4; ++g) { bi1[g] = b1[g * kUNIT + u]; bi2[g] = b2[g * kUNIT + u]; }

  for (int t = 0; t < tmax; ++t) {
    // ---- stage x_t into LDS (transposed [d][r]) ----
    for (int idx = u; idx < D * ROWS; idx += 256) {
      int r = idx / D;
      int d = idx - r * D;
      float v;
      if constexpr (MODE == 0) {
        int so = order[(row0 + r) * STEPS + t];
        v = xsrc[((size_t)(row0 + r) * kT + so) * kFC + d];
      } else if constexpr (MODE == 1) {
        v = xsrc[((size_t)(row0 + r) * kT + t) * kFC + d];
      } else {
        int aid = order[(row0 + r) * STEPS + t];
        v = xsrc[aid * 50 + d];
      }
      xs[d * ROWS + r] = v;
    }
    __syncthreads();

    // ---- layer 1 ----
    float a0[ROWS], a1[ROWS], a2[ROWS], a3[ROWS];
#pragma unroll
    for (int r = 0; r < ROWS; ++r) { a0[r] = bi1[0]; a1[r] = bi1[1]; a2[r] = bi1[2]; a3[r] = bi1[3]; }

#pragma unroll 8
    for (int k = 0; k < D; ++k) {
      float4 w = *reinterpret_cast<const float4*>(W1r + (size_t)(k * 256 + u) * 4);
      float xv[ROWS];
      ldsvec<ROWS>(xs + k * ROWS, xv);
#pragma unroll
      for (int r = 0; r < ROWS; ++r) {
        a0[r] = fmaf(xv[r], w.x, a0[r]);
        a1[r] = fmaf(xv[r], w.y, a1[r]);
        a2[r] = fmaf(xv[r], w.z, a2[r]);
        a3[r] = fmaf(xv[r], w.w, a3[r]);
      }
    }
#pragma unroll 8
    for (int k = 0; k < kUNIT; ++k) {
      float4 w = *reinterpret_cast<const float4*>(W1r + (size_t)((D + k) * 256 + u) * 4);
      float xv[ROWS];
      ldsvec<ROWS>(h1s + k * ROWS, xv);
#pragma unroll
      for (int r = 0; r < ROWS; ++r) {
        a0[r] = fmaf(xv[r], w.x, a0[r]);
        a1[r] = fmaf(xv[r], w.y, a1[r]);
        a2[r] = fmaf(xv[r], w.z, a2[r]);
        a3[r] = fmaf(xv[r], w.w, a3[r]);
      }
    }
    __syncthreads();  // all threads done reading h1s/xs

    float x2v[ROWS];
#pragma unroll
    for (int r = 0; r < ROWS; ++r) {
      float iv = sigf(a0[r]);
      float jv = tanhf(a1[r]);
      float fv = sigf(a2[r] + 1.0f);
      float ov = sigf(a3[r]);
      float nc = fv * c1[r] + iv * jv;
      float nh = ov * tanhf(nc);
      x2v[r] = nh;              // layer-2 input is the UNMASKED nh1 (per reference)
      if (t < len[r]) { c1[r] = nc; h1reg[r] = nh; }
    }
    stsvec<ROWS>(x2s + u * ROWS, x2v);
    stsvec<ROWS>(h1s + u * ROWS, h1reg);
    __syncthreads();

    // ---- layer 2 ----
#pragma unroll
    for (int r = 0; r < ROWS; ++r) { a0[r] = bi2[0]; a1[r] = bi2[1]; a2[r] = bi2[2]; a3[r] = bi2[3]; }

#pragma unroll 8
    for (int k = 0; k < kUNIT; ++k) {
      float4 w = *reinterpret_cast<const float4*>(W2r + (size_t)(k * 256 + u) * 4);
      float xv[ROWS];
      ldsvec<ROWS>(x2s + k * ROWS, xv);
#pragma unroll
      for (int r = 0; r < ROWS; ++r) {
        a0[r] = fmaf(xv[r], w.x, a0[r]);
        a1[r] = fmaf(xv[r], w.y, a1[r]);
        a2[r] = fmaf(xv[r], w.z, a2[r]);
        a3[r] = fmaf(xv[r], w.w, a3[r]);
      }
    }
#pragma unroll 8
    for (int k = 0; k < kUNIT; ++k) {
      float4 w = *reinterpret_cast<const float4*>(W2r + (size_t)((kUNIT + k) * 256 + u) * 4);
      float xv[ROWS];
      ldsvec<ROWS>(h2s + k * ROWS, xv);
#pragma unroll
      for (int r = 0; r < ROWS; ++r) {
        a0[r] = fmaf(xv[r], w.x, a0[r]);
        a1[r] = fmaf(xv[r], w.y, a1[r]);
        a2[r] = fmaf(xv[r], w.z, a2[r]);
        a3[r] = fmaf(xv[r], w.w, a3[r]);
      }
    }
    __syncthreads();  // all threads done reading h2s/x2s

#pragma unroll
    for (int r = 0; r < ROWS; ++r) {
      float iv = sigf(a0[r]);
      float jv = tanhf(a1[r]);
      float fv = sigf(a2[r] + 1.0f);
      float ov = sigf(a3[r]);
      float nc = fv * c2[r] + iv * jv;
      float nh = ov * tanhf(nc);
      if (t < len[r]) { c2[r] = nc; h2reg[r] = nh; }
    }
    stsvec<ROWS>(h2s + u * ROWS, h2reg);
    __syncthreads();
  }

#pragma unroll
  for (int r = 0; r < ROWS; ++r)
    hcat[(size_t)(row0 + r) * 768 + hoff + u] = h2reg[r];
}

__global__ __launch_bounds__(256) void lstm_all_kernel(
    const float* __restrict__ res_g, const float* __restrict__ buff_emb,
    const float* __restrict__ W_act,
    const int* __restrict__ sord, const int* __restrict__ haid,
    const int* __restrict__ slen, const int* __restrict__ blen, const int* __restrict__ alen,
    const float* __restrict__ sW1r, const float* __restrict__ sb1,
    const float* __restrict__ sW2r, const float* __restrict__ sb2,
    const float* __restrict__ bW1r, const float* __restrict__ bb1,
    const float* __restrict__ bW2r, const float* __restrict__ bb2,
    const float* __restrict__ aW1r, const float* __restrict__ ab1,
    const float* __restrict__ aW2r, const float* __restrict__ ab2,
    float* __restrict__ hcat) {
  extern __shared__ float smem[];
  const int blk = blockIdx.x;
  if (blk < 64) {
    lstm_body<4, 128, 128, 0>(blk, smem, res_g, sord, slen, sW1r, sb1, sW2r, sb2, hcat, 0);
  } else if (blk < 128) {
    lstm_body<4, 128, 128, 1>(blk - 64, smem, buff_emb, nullptr, blen, bW1r, bb1, bW2r, bb2, hcat, 256);
  } else {
    lstm_body<2, 50, 256, 2>(blk - 128, smem, W_act, haid, alen, aW1r, ab1, aW2r, ab2, hcat, 512);
  }
}

// ---------------------------------------------------------------------------
// Final projection: out[b] = hcat[b] @ fW + fb   (256 x 768) @ (768 x 82)
// ---------------------------------------------------------------------------
__global__ __launch_bounds__(128) void final_kernel(
    const float* __restrict__ hcat, const float* __restrict__ fW,
    const float* __restrict__ fb, float* __restrict__ out) {
  __shared__ float hrow[768];
  const int b = blockIdx.x;
  const int tid = threadIdx.x;
  for (int k = tid; k < 768; k += 128) hrow[k] = hcat[(size_t)b * 768 + k];
  __syncthreads();
  if (tid < kNACT) {
    float acc = fb[tid];
#pragma unroll 8
    for (int k = 0; k < 768; ++k) acc = fmaf(hrow[k], fW[k * kNACT + tid], acc);
    out[(size_t)b * kNACT + tid] = acc;
  }
}

}  // namespace

extern "C" void kernel_launch(void* const* d_in, const int* in_sizes, int n_in,
                              void* d_out, int out_size, void* d_ws, size_t ws_size,
                              hipStream_t stream) {
  const int* twid = (const int*)d_in[0];
  const int* tpid = (const int*)d_in[1];
  const int* bwid = (const int*)d_in[2];
  const int* bpid = (const int*)d_in[3];
  const int* relid = (const int*)d_in[4];
  const int* haid = (const int*)d_in[5];
  const int* head = (const int*)d_in[6];
  const int* depo = (const int*)d_in[7];
  const int* leaf = (const int*)d_in[8];
  const int* sord = (const int*)d_in[9];
  const int* slen = (const int*)d_in[10];
  const int* blen = (const int*)d_in[11];
  const int* alen = (const int*)d_in[12];
  const float* W_word = (const float*)d_in[13];
  const float* W_pos = (const float*)d_in[14];
  const float* W_rel = (const float*)d_in[15];
  const float* W_act = (const float*)d_in[16];
  const float* emb_W = (const float*)d_in[17];
  const float* emb_b = (const float*)d_in[18];
  const float* rec_W = (const float*)d_in[19];
  const float* rec_b = (const float*)d_in[20];
  const float* sW1 = (const float*)d_in[21];
  const float* sb1 = (const float*)d_in[22];
  const float* sW2 = (const float*)d_in[23];
  const float* sb2 = (const float*)d_in[24];
  const float* bW1 = (const float*)d_in[25];
  const float* bb1 = (const float*)d_in[26];
  const float* bW2 = (const float*)d_in[27];
  const float* bb2 = (const float*)d_in[28];
  const float* aW1 = (const float*)d_in[29];
  const float* ab1 = (const float*)d_in[30];
  const float* aW2 = (const float*)d_in[31];
  const float* ab2 = (const float*)d_in[32];
  const float* fW = (const float*)d_in[33];
  const float* fb = (const float*)d_in[34];

  // workspace carve-up (floats)
  float* ws = (float*)d_ws;
  float* tree_emb = ws;                                   // 256*128*128
  float* buff_emb = tree_emb + kB * kT * kFC;             // 256*128*128
  float* res_g    = buff_emb + kB * kT * kFC;             // 256*128*128
  float* hcat     = res_g + kB * kT * kFC;                // 256*768
  float* sW1r = hcat + kB * 768;                          // 384*1024
  float* sW2r = sW1r + 384 * 1024;                        // 512*1024
  float* bW1r = sW2r + 512 * 1024;                        // 384*1024
  float* bW2r = bW1r + 384 * 1024;                        // 512*1024
  float* aW1r = bW2r + 512 * 1024;                        // 306*1024
  float* aW2r = aW1r + 306 * 1024;                        // 512*1024
  size_t needed = (size_t)(aW2r + 512 * 1024 - ws) * sizeof(float);
  if (ws_size < needed) return;  // fail loudly via validation rather than corrupt

  // 1) gate-interleave the six LSTM weight matrices
  auto reorder = [&](const float* W, float* Wr, int K) {
    int total = K * 1024;
    reorder_w_kernel<<<(total + 255) / 256, 256, 0, stream>>>(W, Wr, K);
  };
  reorder(sW1, sW1r, 384);
  reorder(sW2, sW2r, 512);
  reorder(bW1, bW1r, 384);
  reorder(bW2, bW2r, 512);
  reorder(aW1, aW1r, 306);
  reorder(aW2, aW2r, 512);

  // 2) embeddings (tree + buff fused)
  emb_kernel<<<(2 * kB * kT) / 8, 128, 0, stream>>>(
      twid, tpid, bwid, bpid, W_word, W_pos, emb_W, emb_b, tree_emb, buff_emb);

  // 3) tree composition scan (one block per batch row)
  tree_scan_kernel<<<kB, 128, 0, stream>>>(
      tree_emb, head, depo, relid, leaf, W_rel, rec_W, rec_b, res_g);

  // 4) all three LSTMs in one launch (256 blocks = 1 per CU)
  constexpr int kSmemBytes = (128 * 4 + 3 * 256 * 4) * (int)sizeof(float);  // 14336
  lstm_all_kernel<<<256, 256, kSmemBytes, stream>>>(
      res_g, buff_emb, W_act, sord, haid, slen, blen, alen,
      sW1r, sb1, sW2r, sb2, bW1r, bb1, bW2r, bb2, aW1r, ab1, aW2r, ab2, hcat);

  // 5) output projection
  final_kernel<<<kB, 128, 0, stream>>>(hcat, fW, fb, (float*)d_out);
}

// Round 2
// 8588.915 us; speedup vs baseline: 1.2532x; 1.2532x over previous
//
#include <hip/hip_runtime.h>
#include <hip/hip_fp16.h>
#include <math.h>

namespace {

constexpr int kB = 256;
constexpr int kT = 128;
constexpr int kFC = 128;
constexpr int kUNIT = 256;
constexpr int kNACT = 82;
constexpr int kWDIM = 300;
constexpr int kPOS = 50;

__device__ __forceinline__ float sigf(float x) { return 1.0f / (1.0f + expf(-x)); }

struct alignas(8) H4 { __half2 lo, hi; };

__device__ __forceinline__ float4 ldw4(const __half* p) {
  H4 h = *reinterpret_cast<const H4*>(p);
  float2 f0 = __half22float2(h.lo);
  float2 f1 = __half22float2(h.hi);
  return make_float4(f0.x, f0.y, f1.x, f1.y);
}

template <int ROWS>
__device__ __forceinline__ void ldsvec(const float* p, float* v) {
  if constexpr (ROWS == 4) {
    float4 t = *reinterpret_cast<const float4*>(p);
    v[0] = t.x; v[1] = t.y; v[2] = t.z; v[3] = t.w;
  } else {
    float2 t = *reinterpret_cast<const float2*>(p);
    v[0] = t.x; v[1] = t.y;
  }
}

template <int ROWS>
__device__ __forceinline__ void stsvec(float* p, const float* v) {
  if constexpr (ROWS == 4) {
    *reinterpret_cast<float4*>(p) = make_float4(v[0], v[1], v[2], v[3]);
  } else {
    *reinterpret_cast<float2*>(p) = make_float2(v[0], v[1]);
  }
}

// ---------------------------------------------------------------------------
// Reorder LSTM weight (K,1024) fp32 row-major -> fp16 Wr[k][u][g]
// ---------------------------------------------------------------------------
__global__ void reorder_w_kernel(const float* __restrict__ W, __half* __restrict__ Wr, int K) {
  int idx = blockIdx.x * 256 + threadIdx.x;
  int total = K * 1024;
  if (idx < total) {
    int k = idx >> 10;
    int c = idx & 1023;
    int u = c >> 2;
    int g = c & 3;
    Wr[idx] = __float2half(W[k * 1024 + g * 256 + u]);
  }
}

// ---------------------------------------------------------------------------
// Embeddings: relu(concat(W_word[wid], W_pos[pid]) @ emb_W + emb_b)
// ---------------------------------------------------------------------------
__global__ __launch_bounds__(128) void emb_kernel(
    const int* __restrict__ twid, const int* __restrict__ tpid,
    const int* __restrict__ bwid, const int* __restrict__ bpid,
    const float* __restrict__ W_word, const float* __restrict__ W_pos,
    const float* __restrict__ emb_W, const float* __restrict__ emb_b,
    float* __restrict__ tree_emb, float* __restrict__ buff_emb) {
  __shared__ float xs[8][352];
  const int tid = threadIdx.x;
  const int pair0 = blockIdx.x * 8;
  const int NTREE = kB * kT;

  for (int p = 0; p < 8; ++p) {
    int P = pair0 + p;
    bool isTree = P < NTREE;
    int idx = isTree ? P : P - NTREE;
    int wid = isTree ? twid[idx] : bwid[idx];
    int pid = isTree ? tpid[idx] : bpid[idx];
    const float* wrow = W_word + (size_t)wid * kWDIM;
    for (int k = tid; k < kWDIM; k += 128) xs[p][k] = wrow[k];
    if (tid < kPOS) xs[p][kWDIM + tid] = W_pos[pid * kPOS + tid];
  }
  __syncthreads();

  float acc[8];
  const float bj = emb_b[tid];
#pragma unroll
  for (int p = 0; p < 8; ++p) acc[p] = bj;

#pragma unroll 10
  for (int k = 0; k < kWDIM + kPOS; ++k) {
    float w = emb_W[k * kFC + tid];
#pragma unroll
    for (int p = 0; p < 8; ++p) acc[p] = fmaf(xs[p][k], w, acc[p]);
  }

  for (int p = 0; p < 8; ++p) {
    int P = pair0 + p;
    bool isTree = P < NTREE;
    int idx = isTree ? P : P - NTREE;
    float v = fmaxf(acc[p], 0.0f);
    (isTree ? tree_emb : buff_emb)[(size_t)idx * kFC + tid] = v;
  }
}

// ---------------------------------------------------------------------------
// Tree composition scan: one block per batch row, res[128][128] fully in LDS.
// ---------------------------------------------------------------------------
__global__ __launch_bounds__(128) void tree_scan_kernel(
    const float* __restrict__ tree_emb,
    const int* __restrict__ head_ord, const int* __restrict__ dep_ord,
    const int* __restrict__ rel_id, const int* __restrict__ is_leaf,
    const float* __restrict__ W_rel,
    const float* __restrict__ rec_W, const float* __restrict__ rec_b,
    float* __restrict__ res_g) {
  __shared__ float res[kT][kFC];  // exactly 64 KB
  const int b = blockIdx.x;
  const int j = threadIdx.x;

  res[0][j] = tree_emb[((size_t)b * kT) * kFC + j];
  const float rb = rec_b[j];
  __syncthreads();

  for (int i = 1; i < kT; ++i) {
    const int base = b * kT + i;
    const int leaf = is_leaf[base];  // uniform across block
    if (leaf > 0) {
      res[i][j] = tree_emb[(size_t)base * kFC + j];
    } else {
      const int hi = head_ord[base];
      const int di = dep_ord[base];
      const int rid = rel_id[base];
      float acc = rb;
#pragma unroll 8
      for (int k = 0; k < 128; ++k)
        acc = fmaf(res[hi][k], rec_W[k * kFC + j], acc);
#pragma unroll 5
      for (int k = 0; k < 50; ++k)
        acc = fmaf(W_rel[rid * 50 + k], rec_W[(128 + k) * kFC + j], acc);
#pragma unroll 8
      for (int k = 0; k < 128; ++k)
        acc = fmaf(res[di][k], rec_W[(178 + k) * kFC + j], acc);
      res[i][j] = tanhf(acc);
    }
    __syncthreads();
  }

  for (int idx = j; idx < kT * kFC; idx += 128) {
    int t = idx >> 7;
    int jj = idx & 127;
    res_g[((size_t)b * kT + t) * kFC + jj] = res[t][jj];
  }
}

// ---------------------------------------------------------------------------
// 2-layer LSTM, batch-split, fp16 weights (gate-interleaved), fp32 state.
// ---------------------------------------------------------------------------
template <int ROWS, int D, int STEPS, int MODE>
__device__ __forceinline__ void lstm_body(
    int blk, float* smem,
    const float* __restrict__ xsrc, const int* __restrict__ order,
    const int* __restrict__ lengths,
    const __half* __restrict__ W1r, const float* __restrict__ b1,
    const __half* __restrict__ W2r, const float* __restrict__ b2,
    float* __restrict__ hcat, int hoff) {
  float* xs  = smem;                    // D*ROWS
  float* h1s = xs + D * ROWS;           // 256*ROWS
  float* x2s = h1s + kUNIT * ROWS;      // 256*ROWS
  float* h2s = x2s + kUNIT * ROWS;      // 256*ROWS

  const int u = threadIdx.x;
  const int row0 = blk * ROWS;

  float c1[ROWS], c2[ROWS], h1reg[ROWS], h2reg[ROWS];
  int len[ROWS];
  int tmax = 0;
#pragma unroll
  for (int r = 0; r < ROWS; ++r) {
    c1[r] = 0.f; c2[r] = 0.f; h1reg[r] = 0.f; h2reg[r] = 0.f;
    len[r] = lengths[row0 + r];
    tmax = len[r] > tmax ? len[r] : tmax;
  }
#pragma unroll
  for (int r = 0; r < ROWS; ++r) { h1s[u * ROWS + r] = 0.f; h2s[u * ROWS + r] = 0.f; }

  float bi1[4], bi2[4];
#pragma unroll
  for (int g = 0; g < 4; ++g) { bi1[g] = b1[g * kUNIT + u]; bi2[g] = b2[g * kUNIT + u]; }

  for (int t = 0; t < tmax; ++t) {
    // ---- stage x_t into LDS (transposed [d][r]) ----
    for (int idx = u; idx < D * ROWS; idx += 256) {
      int r = idx / D;
      int d = idx - r * D;
      float v;
      if constexpr (MODE == 0) {
        int so = order[(row0 + r) * STEPS + t];
        v = xsrc[((size_t)(row0 + r) * kT + so) * kFC + d];
      } else if constexpr (MODE == 1) {
        v = xsrc[((size_t)(row0 + r) * kT + t) * kFC + d];
      } else {
        int aid = order[(row0 + r) * STEPS + t];
        v = xsrc[aid * 50 + d];
      }
      xs[d * ROWS + r] = v;
    }
    __syncthreads();

    // ---- layer 1 ----
    float a0[ROWS], a1[ROWS], a2[ROWS], a3[ROWS];
#pragma unroll
    for (int r = 0; r < ROWS; ++r) { a0[r] = bi1[0]; a1[r] = bi1[1]; a2[r] = bi1[2]; a3[r] = bi1[3]; }

#pragma unroll 8
    for (int k = 0; k < D; ++k) {
      float4 w = ldw4(W1r + (size_t)(k * 256 + u) * 4);
      float xv[ROWS];
      ldsvec<ROWS>(xs + k * ROWS, xv);
#pragma unroll
      for (int r = 0; r < ROWS; ++r) {
        a0[r] = fmaf(xv[r], w.x, a0[r]);
        a1[r] = fmaf(xv[r], w.y, a1[r]);
        a2[r] = fmaf(xv[r], w.z, a2[r]);
        a3[r] = fmaf(xv[r], w.w, a3[r]);
      }
    }
#pragma unroll 8
    for (int k = 0; k < kUNIT; ++k) {
      float4 w = ldw4(W1r + (size_t)((D + k) * 256 + u) * 4);
      float xv[ROWS];
      ldsvec<ROWS>(h1s + k * ROWS, xv);
#pragma unroll
      for (int r = 0; r < ROWS; ++r) {
        a0[r] = fmaf(xv[r], w.x, a0[r]);
        a1[r] = fmaf(xv[r], w.y, a1[r]);
        a2[r] = fmaf(xv[r], w.z, a2[r]);
        a3[r] = fmaf(xv[r], w.w, a3[r]);
      }
    }
    __syncthreads();  // all threads done reading h1s/xs

    float x2v[ROWS];
#pragma unroll
    for (int r = 0; r < ROWS; ++r) {
      float iv = sigf(a0[r]);
      float jv = tanhf(a1[r]);
      float fv = sigf(a2[r] + 1.0f);
      float ov = sigf(a3[r]);
      float nc = fv * c1[r] + iv * jv;
      float nh = ov * tanhf(nc);
      x2v[r] = nh;              // layer-2 input is the UNMASKED nh1 (per reference)
      if (t < len[r]) { c1[r] = nc; h1reg[r] = nh; }
    }
    stsvec<ROWS>(x2s + u * ROWS, x2v);
    stsvec<ROWS>(h1s + u * ROWS, h1reg);
    __syncthreads();

    // ---- layer 2 ----
#pragma unroll
    for (int r = 0; r < ROWS; ++r) { a0[r] = bi2[0]; a1[r] = bi2[1]; a2[r] = bi2[2]; a3[r] = bi2[3]; }

#pragma unroll 8
    for (int k = 0; k < kUNIT; ++k) {
      float4 w = ldw4(W2r + (size_t)(k * 256 + u) * 4);
      float xv[ROWS];
      ldsvec<ROWS>(x2s + k * ROWS, xv);
#pragma unroll
      for (int r = 0; r < ROWS; ++r) {
        a0[r] = fmaf(xv[r], w.x, a0[r]);
        a1[r] = fmaf(xv[r], w.y, a1[r]);
        a2[r] = fmaf(xv[r], w.z, a2[r]);
        a3[r] = fmaf(xv[r], w.w, a3[r]);
      }
    }
#pragma unroll 8
    for (int k = 0; k < kUNIT; ++k) {
      float4 w = ldw4(W2r + (size_t)((kUNIT + k) * 256 + u) * 4);
      float xv[ROWS];
      ldsvec<ROWS>(h2s + k * ROWS, xv);
#pragma unroll
      for (int r = 0; r < ROWS; ++r) {
        a0[r] = fmaf(xv[r], w.x, a0[r]);
        a1[r] = fmaf(xv[r], w.y, a1[r]);
        a2[r] = fmaf(xv[r], w.z, a2[r]);
        a3[r] = fmaf(xv[r], w.w, a3[r]);
      }
    }
    __syncthreads();  // all threads done reading h2s/x2s

#pragma unroll
    for (int r = 0; r < ROWS; ++r) {
      float iv = sigf(a0[r]);
      float jv = tanhf(a1[r]);
      float fv = sigf(a2[r] + 1.0f);
      float ov = sigf(a3[r]);
      float nc = fv * c2[r] + iv * jv;
      float nh = ov * tanhf(nc);
      if (t < len[r]) { c2[r] = nc; h2reg[r] = nh; }
    }
    stsvec<ROWS>(h2s + u * ROWS, h2reg);
    __syncthreads();
  }

#pragma unroll
  for (int r = 0; r < ROWS; ++r)
    hcat[(size_t)(row0 + r) * 768 + hoff + u] = h2reg[r];
}

// XCD-aware: dispatch maps blockIdx.x -> XCD (blockIdx.x % 8). Pin each LSTM's
// weight working set (~1.8 MB fp16) to dedicated XCDs so it stays L2-resident:
// stack -> XCD{0,1}, buff -> XCD{2,3}, act -> XCD{4..7}.
__global__ __launch_bounds__(256) void lstm_all_kernel(
    const float* __restrict__ res_g, const float* __restrict__ buff_emb,
    const float* __restrict__ W_act,
    const int* __restrict__ sord, const int* __restrict__ haid,
    const int* __restrict__ slen, const int* __restrict__ blen, const int* __restrict__ alen,
    const __half* __restrict__ sW1r, const float* __restrict__ sb1,
    const __half* __restrict__ sW2r, const float* __restrict__ sb2,
    const __half* __restrict__ bW1r, const float* __restrict__ bb1,
    const __half* __restrict__ bW2r, const float* __restrict__ bb2,
    const __half* __restrict__ aW1r, const float* __restrict__ ab1,
    const __half* __restrict__ aW2r, const float* __restrict__ ab2,
    float* __restrict__ hcat) {
  extern __shared__ float smem[];
  const int xcd = blockIdx.x & 7;
  const int slot = blockIdx.x >> 3;  // 0..31
  if (xcd < 2) {
    lstm_body<4, 128, 128, 0>(xcd * 32 + slot, smem, res_g, sord, slen, sW1r, sb1, sW2r, sb2, hcat, 0);
  } else if (xcd < 4) {
    lstm_body<4, 128, 128, 1>((xcd - 2) * 32 + slot, smem, buff_emb, nullptr, blen, bW1r, bb1, bW2r, bb2, hcat, 256);
  } else {
    lstm_body<2, 50, 256, 2>((xcd - 4) * 32 + slot, smem, W_act, haid, alen, aW1r, ab1, aW2r, ab2, hcat, 512);
  }
}

// ---------------------------------------------------------------------------
// Final projection: out[b] = hcat[b] @ fW + fb   (256 x 768) @ (768 x 82)
// ---------------------------------------------------------------------------
__global__ __launch_bounds__(128) void final_kernel(
    const float* __restrict__ hcat, const float* __restrict__ fW,
    const float* __restrict__ fb, float* __restrict__ out) {
  __shared__ float hrow[768];
  const int b = blockIdx.x;
  const int tid = threadIdx.x;
  for (int k = tid; k < 768; k += 128) hrow[k] = hcat[(size_t)b * 768 + k];
  __syncthreads();
  if (tid < kNACT) {
    float acc = fb[tid];
#pragma unroll 8
    for (int k = 0; k < 768; ++k) acc = fmaf(hrow[k], fW[k * kNACT + tid], acc);
    out[(size_t)b * kNACT + tid] = acc;
  }
}

}  // namespace

extern "C" void kernel_launch(void* const* d_in, const int* in_sizes, int n_in,
                              void* d_out, int out_size, void* d_ws, size_t ws_size,
                              hipStream_t stream) {
  const int* twid = (const int*)d_in[0];
  const int* tpid = (const int*)d_in[1];
  const int* bwid = (const int*)d_in[2];
  const int* bpid = (const int*)d_in[3];
  const int* relid = (const int*)d_in[4];
  const int* haid = (const int*)d_in[5];
  const int* head = (const int*)d_in[6];
  const int* depo = (const int*)d_in[7];
  const int* leaf = (const int*)d_in[8];
  const int* sord = (const int*)d_in[9];
  const int* slen = (const int*)d_in[10];
  const int* blen = (const int*)d_in[11];
  const int* alen = (const int*)d_in[12];
  const float* W_word = (const float*)d_in[13];
  const float* W_pos = (const float*)d_in[14];
  const float* W_rel = (const float*)d_in[15];
  const float* W_act = (const float*)d_in[16];
  const float* emb_W = (const float*)d_in[17];
  const float* emb_b = (const float*)d_in[18];
  const float* rec_W = (const float*)d_in[19];
  const float* rec_b = (const float*)d_in[20];
  const float* sW1 = (const float*)d_in[21];
  const float* sb1 = (const float*)d_in[22];
  const float* sW2 = (const float*)d_in[23];
  const float* sb2 = (const float*)d_in[24];
  const float* bW1 = (const float*)d_in[25];
  const float* bb1 = (const float*)d_in[26];
  const float* bW2 = (const float*)d_in[27];
  const float* bb2 = (const float*)d_in[28];
  const float* aW1 = (const float*)d_in[29];
  const float* ab1 = (const float*)d_in[30];
  const float* aW2 = (const float*)d_in[31];
  const float* ab2 = (const float*)d_in[32];
  const float* fW = (const float*)d_in[33];
  const float* fb = (const float*)d_in[34];

  // workspace carve-up
  float* ws = (float*)d_ws;
  float* tree_emb = ws;                                   // 256*128*128 f32
  float* buff_emb = tree_emb + kB * kT * kFC;             // 256*128*128 f32
  float* res_g    = buff_emb + kB * kT * kFC;             // 256*128*128 f32
  float* hcat     = res_g + kB * kT * kFC;                // 256*768 f32
  __half* wh = (__half*)(hcat + kB * 768);
  __half* sW1r = wh;                                      // 384*1024 f16
  __half* sW2r = sW1r + 384 * 1024;                       // 512*1024 f16
  __half* bW1r = sW2r + 512 * 1024;                       // 384*1024 f16
  __half* bW2r = bW1r + 384 * 1024;                       // 512*1024 f16
  __half* aW1r = bW2r + 512 * 1024;                       // 306*1024 f16
  __half* aW2r = aW1r + 306 * 1024;                       // 512*1024 f16
  size_t needed = (size_t)((char*)(aW2r + 512 * 1024) - (char*)ws);
  if (ws_size < needed) return;

  // 1) gate-interleave + fp16-cast the six LSTM weight matrices
  auto reorder = [&](const float* W, __half* Wr, int K) {
    int total = K * 1024;
    reorder_w_kernel<<<(total + 255) / 256, 256, 0, stream>>>(W, Wr, K);
  };
  reorder(sW1, sW1r, 384);
  reorder(sW2, sW2r, 512);
  reorder(bW1, bW1r, 384);
  reorder(bW2, bW2r, 512);
  reorder(aW1, aW1r, 306);
  reorder(aW2, aW2r, 512);

  // 2) embeddings (tree + buff fused)
  emb_kernel<<<(2 * kB * kT) / 8, 128, 0, stream>>>(
      twid, tpid, bwid, bpid, W_word, W_pos, emb_W, emb_b, tree_emb, buff_emb);

  // 3) tree composition scan (one block per batch row)
  tree_scan_kernel<<<kB, 128, 0, stream>>>(
      tree_emb, head, depo, relid, leaf, W_rel, rec_W, rec_b, res_g);

  // 4) all three LSTMs in one launch, XCD-partitioned
  constexpr int kSmemBytes = (128 * 4 + 3 * 256 * 4) * (int)sizeof(float);  // 14336
  lstm_all_kernel<<<256, 256, kSmemBytes, stream>>>(
      res_g, buff_emb, W_act, sord, haid, slen, blen, alen,
      sW1r, sb1, sW2r, sb2, bW1r, bb1, bW2r, bb2, aW1r, ab1, aW2r, ab2, hcat);

  // 5) output projection
  final_kernel<<<kB, 128, 0, stream>>>(hcat, fW, fb, (float*)d_out);
}

// Round 3
// 8532.126 us; speedup vs baseline: 1.2615x; 1.0067x over previous
//
#include <hip/hip_runtime.h>
#include <hip/hip_fp16.h>
#include <math.h>

namespace {

constexpr int kB = 256;
constexpr int kT = 128;
constexpr int kFC = 128;
constexpr int kNACT = 82;
constexpr int kWDIM = 300;
constexpr int kPOS = 50;

typedef _Float16 v4h __attribute__((ext_vector_type(4)));
typedef _Float16 v2h __attribute__((ext_vector_type(2)));
typedef float f32x4 __attribute__((ext_vector_type(4)));

__device__ __forceinline__ float sigf(float x) { return 1.0f / (1.0f + expf(-x)); }

#define LOAD_LDS16(gp, lp)                                            \
  __builtin_amdgcn_global_load_lds(                                   \
      (const __attribute__((address_space(1))) void*)(gp),            \
      (__attribute__((address_space(3))) void*)(lp), 16, 0, 0)

// ---------------------------------------------------------------------------
// Reorder LSTM weight (K,1024) fp32 -> fp16 Wr[kchunk16][col'=4u+g][k_in_16]
// with optional x-section padding (rows [D,Dpad) are zero).
// ---------------------------------------------------------------------------
__global__ void reorder_w_kernel(const float* __restrict__ W, _Float16* __restrict__ Wr,
                                 int Kpad, int D, int Dpad) {
  int idx = blockIdx.x * 256 + threadIdx.x;
  int total = Kpad * 1024;
  if (idx >= total) return;
  int c = idx >> 14;          // /16384
  int rem = idx & 16383;
  int col = rem >> 4;
  int ki = rem & 15;
  int k = c * 16 + ki;
  int u = col >> 2, g = col & 3;
  int src;
  if (k < Dpad) src = (k < D) ? k : -1;
  else src = D + (k - Dpad);
  Wr[idx] = (src >= 0) ? (_Float16)W[(size_t)src * 1024 + g * 256 + u] : (_Float16)0.f;
}

// ---------------------------------------------------------------------------
// Embeddings: relu(concat(W_word[wid], W_pos[pid]) @ emb_W + emb_b)
// ---------------------------------------------------------------------------
__global__ __launch_bounds__(128) void emb_kernel(
    const int* __restrict__ twid, const int* __restrict__ tpid,
    const int* __restrict__ bwid, const int* __restrict__ bpid,
    const float* __restrict__ W_word, const float* __restrict__ W_pos,
    const float* __restrict__ emb_W, const float* __restrict__ emb_b,
    float* __restrict__ tree_emb, float* __restrict__ buff_emb) {
  __shared__ float xs[8][352];
  const int tid = threadIdx.x;
  const int pair0 = blockIdx.x * 8;
  const int NTREE = kB * kT;

  for (int p = 0; p < 8; ++p) {
    int P = pair0 + p;
    bool isTree = P < NTREE;
    int idx = isTree ? P : P - NTREE;
    int wid = isTree ? twid[idx] : bwid[idx];
    int pid = isTree ? tpid[idx] : bpid[idx];
    const float* wrow = W_word + (size_t)wid * kWDIM;
    for (int k = tid; k < kWDIM; k += 128) xs[p][k] = wrow[k];
    if (tid < kPOS) xs[p][kWDIM + tid] = W_pos[pid * kPOS + tid];
  }
  __syncthreads();

  float acc[8];
  const float bj = emb_b[tid];
#pragma unroll
  for (int p = 0; p < 8; ++p) acc[p] = bj;

#pragma unroll 10
  for (int k = 0; k < kWDIM + kPOS; ++k) {
    float w = emb_W[k * kFC + tid];
#pragma unroll
    for (int p = 0; p < 8; ++p) acc[p] = fmaf(xs[p][k], w, acc[p]);
  }

  for (int p = 0; p < 8; ++p) {
    int P = pair0 + p;
    bool isTree = P < NTREE;
    int idx = isTree ? P : P - NTREE;
    float v = fmaxf(acc[p], 0.0f);
    (isTree ? tree_emb : buff_emb)[(size_t)idx * kFC + tid] = v;
  }
}

// ---------------------------------------------------------------------------
// Tree composition scan: one block per batch row, res[128][128] fully in LDS.
// ---------------------------------------------------------------------------
__global__ __launch_bounds__(128) void tree_scan_kernel(
    const float* __restrict__ tree_emb,
    const int* __restrict__ head_ord, const int* __restrict__ dep_ord,
    const int* __restrict__ rel_id, const int* __restrict__ is_leaf,
    const float* __restrict__ W_rel,
    const float* __restrict__ rec_W, const float* __restrict__ rec_b,
    float* __restrict__ res_g) {
  __shared__ float res[kT][kFC];
  const int b = blockIdx.x;
  const int j = threadIdx.x;

  res[0][j] = tree_emb[((size_t)b * kT) * kFC + j];
  const float rb = rec_b[j];
  __syncthreads();

  for (int i = 1; i < kT; ++i) {
    const int base = b * kT + i;
    const int leaf = is_leaf[base];
    if (leaf > 0) {
      res[i][j] = tree_emb[(size_t)base * kFC + j];
    } else {
      const int hi = head_ord[base];
      const int di = dep_ord[base];
      const int rid = rel_id[base];
      float acc = rb;
#pragma unroll 8
      for (int k = 0; k < 128; ++k)
        acc = fmaf(res[hi][k], rec_W[k * kFC + j], acc);
#pragma unroll 5
      for (int k = 0; k < 50; ++k)
        acc = fmaf(W_rel[rid * 50 + k], rec_W[(128 + k) * kFC + j], acc);
#pragma unroll 8
      for (int k = 0; k < 128; ++k)
        acc = fmaf(res[di][k], rec_W[(178 + k) * kFC + j], acc);
      res[i][j] = tanhf(acc);
    }
    __syncthreads();
  }

  for (int idx = j; idx < kT * kFC; idx += 128) {
    int t = idx >> 7;
    int jj = idx & 127;
    res_g[((size_t)b * kT + t) * kFC + jj] = res[t][jj];
  }
}

// ---------------------------------------------------------------------------
// Streamed GEMM layer: z[16 x 1024] += X[16 x K] @ W[K x 1024], fp16 in, f32 acc.
// W chunks (16k x 1024 cols, 32KB) double-buffered in LDS via global_load_lds.
// Each wave owns cols [128w, 128w+128): writes AND reads only its own slice,
// so no barriers inside the chunk loop (per-wave counted vmcnt only).
// ---------------------------------------------------------------------------
template <int NCH>
__device__ __forceinline__ void gemm_stream(
    const _Float16* __restrict__ Wr, _Float16* wbuf,
    const _Float16* xb, int pitch, int lane, int wave, f32x4 (&acc)[8]) {
  const _Float16* gsrc = Wr + wave * 2048 + lane * 8;
  _Float16* lds0 = wbuf + wave * 2048;
  _Float16* lds1 = wbuf + 16384 + wave * 2048;

  {
    const _Float16* gp = gsrc;
#pragma unroll
    for (int it = 0; it < 4; ++it) LOAD_LDS16(gp + it * 512, lds0 + it * 512);
  }

  const _Float16* xr = xb + (lane & 15) * pitch + (lane >> 4) * 4;
  const int bbase = (128 * wave + (lane & 15)) * 16 + (lane >> 4) * 4;

  for (int c = 0; c < NCH; ++c) {
    if (c + 1 < NCH) {
      const _Float16* gp = gsrc + (size_t)(c + 1) * 16384;
      _Float16* lb = ((c + 1) & 1) ? lds1 : lds0;
#pragma unroll
      for (int it = 0; it < 4; ++it) LOAD_LDS16(gp + it * 512, lb + it * 512);
      asm volatile("s_waitcnt vmcnt(4)" ::: "memory");
    } else {
      asm volatile("s_waitcnt vmcnt(0)" ::: "memory");
    }
    __builtin_amdgcn_sched_barrier(0);

    v4h a = *(const v4h*)(xr + c * 16);
    const _Float16* wp = wbuf + ((c & 1) ? 16384 : 0) + bbase;
#pragma unroll
    for (int q = 0; q < 8; ++q) {
      v4h b = *(const v4h*)(wp + q * 256);
      acc[q] = __builtin_amdgcn_mfma_f32_16x16x16f16(a, b, acc[q], 0, 0, 0);
    }
  }
}

// 4x4 transpose across lane quads (regs <-> lanes), 2 butterfly stages.
__device__ __forceinline__ void quadT(int lane, float& a0, float& a1, float& a2, float& a3) {
  {
    bool odd = lane & 1;
    float s0 = odd ? a0 : a1;
    float s1 = odd ? a2 : a3;
    float r0 = __shfl_xor(s0, 1);
    float r1 = __shfl_xor(s1, 1);
    if (odd) { a0 = r0; a2 = r1; } else { a1 = r0; a3 = r1; }
  }
  {
    bool hi = lane & 2;
    float s0 = hi ? a0 : a2;
    float s1 = hi ? a1 : a3;
    float r0 = __shfl_xor(s0, 2);
    float r1 = __shfl_xor(s1, 2);
    if (hi) { a0 = r0; a1 = r1; } else { a2 = r0; a3 = r1; }
  }
}

// ---------------------------------------------------------------------------
// 2-layer LSTM, 16 batch rows per block, 512 threads (8 waves), MFMA fp16.
// MODE 0: stack (gather res_g via stack_order); 1: buff; 2: act (gather W_act).
// ---------------------------------------------------------------------------
template <int MODE, int D, int Dpad, int K1, int NCH1, int STEPS, int P1>
__device__ void lstm16_body(
    int g, _Float16* wbuf, _Float16* xbuf,
    const float* __restrict__ xsrc, const int* __restrict__ order,
    const int* __restrict__ lengths,
    const _Float16* __restrict__ W1r, const float* __restrict__ b1,
    const _Float16* __restrict__ W2r, const float* __restrict__ b2,
    float* __restrict__ hcat, int hoff) {
  constexpr int NCH2 = 32;
  constexpr int P2 = 520;
  _Float16* x1 = xbuf;              // [16][P1]
  _Float16* x2 = xbuf + 16 * 392;   // [16][P2]

  const int tid = threadIdx.x;
  const int lane = tid & 63;
  const int wave = tid >> 6;
  const int row0 = g * 16;

  // zero xbuf (h sections + pads)
  for (int i = tid; i < 16 * 392 + 16 * 520; i += 512) xbuf[i] = (_Float16)0.f;

  const int kgrp = lane >> 4;
  const int prow = kgrp * 4 + (lane & 3);      // pointwise-owned row
  const int ulocal = (lane & 15) >> 2;

  const int lenlane = lengths[row0 + prow];
  int lmax = lengths[row0 + (lane & 15)];
#pragma unroll
  for (int d = 1; d < 16; d <<= 1) { int o = __shfl_xor(lmax, d); lmax = max(lmax, o); }
  const int tmax = lmax;

  float breg1[8][4], breg2[8][4];
  float c1k[8], c2k[8], h1k[8], h2k[8];
#pragma unroll
  for (int q = 0; q < 8; ++q) {
    int unit = 32 * wave + 4 * q + ulocal;
#pragma unroll
    for (int gg = 0; gg < 4; ++gg) {
      breg1[q][gg] = b1[gg * 256 + unit];
      breg2[q][gg] = b2[gg * 256 + unit];
    }
    c1k[q] = c2k[q] = h1k[q] = h2k[q] = 0.f;
  }
  __syncthreads();

  f32x4 acc[8];

  for (int t = 0; t < tmax; ++t) {
    // ---- gather x_t into x1 x-section (fp16) ----
    {
      int r = tid >> 5;
      if constexpr (MODE == 0) {
        int d4 = (tid & 31) * 4;
        int so = order[(row0 + r) * 128 + t];
        float4 v = *(const float4*)(xsrc + ((size_t)(row0 + r) * 128 + so) * 128 + d4);
        v4h h; h[0] = (_Float16)v.x; h[1] = (_Float16)v.y; h[2] = (_Float16)v.z; h[3] = (_Float16)v.w;
        *(v4h*)(x1 + r * P1 + d4) = h;
      } else if constexpr (MODE == 1) {
        int d4 = (tid & 31) * 4;
        float4 v = *(const float4*)(xsrc + ((size_t)(row0 + r) * 128 + t) * 128 + d4);
        v4h h; h[0] = (_Float16)v.x; h[1] = (_Float16)v.y; h[2] = (_Float16)v.z; h[3] = (_Float16)v.w;
        *(v4h*)(x1 + r * P1 + d4) = h;
      } else {
        int d2 = (tid & 31) * 2;
        int aid = order[(row0 + r) * 256 + t];
        float v0 = (d2 < 50) ? xsrc[aid * 50 + d2] : 0.f;
        float v1 = (d2 + 1 < 50) ? xsrc[aid * 50 + d2 + 1] : 0.f;
        v2h h; h[0] = (_Float16)v0; h[1] = (_Float16)v1;
        *(v2h*)(x1 + r * P1 + d2) = h;
      }
    }
    __syncthreads();  // x1 ready (x-section now, h-section from prev step)

    // ---- layer 1 ----
#pragma unroll
    for (int q = 0; q < 8; ++q) { acc[q][0] = 0.f; acc[q][1] = 0.f; acc[q][2] = 0.f; acc[q][3] = 0.f; }
    gemm_stream<NCH1>(W1r, wbuf, x1, P1, lane, wave, acc);
    __syncthreads();  // all waves done reading x1

#pragma unroll
    for (int q = 0; q < 8; ++q) {
      float g0 = acc[q][0], g1 = acc[q][1], g2 = acc[q][2], g3 = acc[q][3];
      quadT(lane, g0, g1, g2, g3);
      int unit = 32 * wave + 4 * q + ulocal;
      float zi = g0 + breg1[q][0];
      float zj = g1 + breg1[q][1];
      float zf = g2 + breg1[q][2];
      float zo = g3 + breg1[q][3];
      float nc = sigf(zf + 1.f) * c1k[q] + sigf(zi) * tanhf(zj);
      float nh = sigf(zo) * tanhf(nc);
      x2[prow * P2 + unit] = (_Float16)nh;            // layer-2 input: UNMASKED nh1
      if (t < lenlane) { c1k[q] = nc; h1k[q] = nh; }
      x1[prow * P1 + Dpad + unit] = (_Float16)h1k[q]; // masked h1 for next step
    }
    __syncthreads();  // x2 ready

    // ---- layer 2 ----
#pragma unroll
    for (int q = 0; q < 8; ++q) { acc[q][0] = 0.f; acc[q][1] = 0.f; acc[q][2] = 0.f; acc[q][3] = 0.f; }
    gemm_stream<NCH2>(W2r, wbuf, x2, P2, lane, wave, acc);
    __syncthreads();  // all waves done reading x2 (h2 section)

#pragma unroll
    for (int q = 0; q < 8; ++q) {
      float g0 = acc[q][0], g1 = acc[q][1], g2 = acc[q][2], g3 = acc[q][3];
      quadT(lane, g0, g1, g2, g3);
      int unit = 32 * wave + 4 * q + ulocal;
      float zi = g0 + breg2[q][0];
      float zj = g1 + breg2[q][1];
      float zf = g2 + breg2[q][2];
      float zo = g3 + breg2[q][3];
      float nc = sigf(zf + 1.f) * c2k[q] + sigf(zi) * tanhf(zj);
      float nh = sigf(zo) * tanhf(nc);
      if (t < lenlane) { c2k[q] = nc; h2k[q] = nh; }
      x2[prow * P2 + 256 + unit] = (_Float16)h2k[q];  // masked h2 for next step
    }
    // next iteration's gather writes only x1 x-section; its barrier joins waves
  }

#pragma unroll
  for (int q = 0; q < 8; ++q) {
    int unit = 32 * wave + 4 * q + ulocal;
    hcat[(size_t)(row0 + prow) * 768 + hoff + unit] = h2k[q];
  }
}

// XCD pinning: blockIdx%8 selects XCD. stack -> XCD{0,1}, buff -> {2,3},
// act -> {4..7} so each LSTM's fp16 weight set stays L2-resident per XCD.
__global__ __launch_bounds__(512, 2) void lstm_mfma_kernel(
    const float* __restrict__ res_g, const float* __restrict__ buff_emb,
    const float* __restrict__ W_act,
    const int* __restrict__ sord, const int* __restrict__ haid,
    const int* __restrict__ slen, const int* __restrict__ blen, const int* __restrict__ alen,
    const _Float16* __restrict__ sW1r, const float* __restrict__ sb1,
    const _Float16* __restrict__ sW2r, const float* __restrict__ sb2,
    const _Float16* __restrict__ bW1r, const float* __restrict__ bb1,
    const _Float16* __restrict__ bW2r, const float* __restrict__ bb2,
    const _Float16* __restrict__ aW1r, const float* __restrict__ ab1,
    const _Float16* __restrict__ aW2r, const float* __restrict__ ab2,
    float* __restrict__ hcat) {
  __shared__ _Float16 wbuf[2 * 16384];            // 64 KB: double-buffered W chunk
  __shared__ _Float16 xbuf[16 * 392 + 16 * 520];  // ~29 KB: X1 | X2 (padded pitches)

  const int x = blockIdx.x & 7;
  const int s = blockIdx.x >> 3;
  if (x < 2) {
    lstm16_body<0, 128, 128, 384, 24, 128, 392>(x * 8 + s, wbuf, xbuf,
        res_g, sord, slen, sW1r, sb1, sW2r, sb2, hcat, 0);
  } else if (x < 4) {
    lstm16_body<1, 128, 128, 384, 24, 128, 392>((x - 2) * 8 + s, wbuf, xbuf,
        buff_emb, nullptr, blen, bW1r, bb1, bW2r, bb2, hcat, 256);
  } else {
    if (s >= 4) return;
    lstm16_body<2, 50, 64, 320, 20, 256, 328>((x - 4) * 4 + s, wbuf, xbuf,
        W_act, haid, alen, aW1r, ab1, aW2r, ab2, hcat, 512);
  }
}

// ---------------------------------------------------------------------------
// Final projection: out[b] = hcat[b] @ fW + fb   (256 x 768) @ (768 x 82)
// ---------------------------------------------------------------------------
__global__ __launch_bounds__(128) void final_kernel(
    const float* __restrict__ hcat, const float* __restrict__ fW,
    const float* __restrict__ fb, float* __restrict__ out) {
  __shared__ float hrow[768];
  const int b = blockIdx.x;
  const int tid = threadIdx.x;
  for (int k = tid; k < 768; k += 128) hrow[k] = hcat[(size_t)b * 768 + k];
  __syncthreads();
  if (tid < kNACT) {
    float acc = fb[tid];
#pragma unroll 8
    for (int k = 0; k < 768; ++k) acc = fmaf(hrow[k], fW[k * kNACT + tid], acc);
    out[(size_t)b * kNACT + tid] = acc;
  }
}

}  // namespace

extern "C" void kernel_launch(void* const* d_in, const int* in_sizes, int n_in,
                              void* d_out, int out_size, void* d_ws, size_t ws_size,
                              hipStream_t stream) {
  const int* twid = (const int*)d_in[0];
  const int* tpid = (const int*)d_in[1];
  const int* bwid = (const int*)d_in[2];
  const int* bpid = (const int*)d_in[3];
  const int* relid = (const int*)d_in[4];
  const int* haid = (const int*)d_in[5];
  const int* head = (const int*)d_in[6];
  const int* depo = (const int*)d_in[7];
  const int* leaf = (const int*)d_in[8];
  const int* sord = (const int*)d_in[9];
  const int* slen = (const int*)d_in[10];
  const int* blen = (const int*)d_in[11];
  const int* alen = (const int*)d_in[12];
  const float* W_word = (const float*)d_in[13];
  const float* W_pos = (const float*)d_in[14];
  const float* W_rel = (const float*)d_in[15];
  const float* W_act = (const float*)d_in[16];
  const float* emb_W = (const float*)d_in[17];
  const float* emb_b = (const float*)d_in[18];
  const float* rec_W = (const float*)d_in[19];
  const float* rec_b = (const float*)d_in[20];
  const float* sW1 = (const float*)d_in[21];
  const float* sb1 = (const float*)d_in[22];
  const float* sW2 = (const float*)d_in[23];
  const float* sb2 = (const float*)d_in[24];
  const float* bW1 = (const float*)d_in[25];
  const float* bb1 = (const float*)d_in[26];
  const float* bW2 = (const float*)d_in[27];
  const float* bb2 = (const float*)d_in[28];
  const float* aW1 = (const float*)d_in[29];
  const float* ab1 = (const float*)d_in[30];
  const float* aW2 = (const float*)d_in[31];
  const float* ab2 = (const float*)d_in[32];
  const float* fW = (const float*)d_in[33];
  const float* fb = (const float*)d_in[34];

  // workspace carve-up
  float* ws = (float*)d_ws;
  float* tree_emb = ws;                                   // 256*128*128 f32
  float* buff_emb = tree_emb + kB * kT * kFC;             // 256*128*128 f32
  float* res_g    = buff_emb + kB * kT * kFC;             // 256*128*128 f32
  float* hcat     = res_g + kB * kT * kFC;                // 256*768 f32
  _Float16* wh = (_Float16*)(hcat + kB * 768);
  _Float16* sW1r = wh;                                    // 384*1024 f16
  _Float16* sW2r = sW1r + 384 * 1024;                     // 512*1024 f16
  _Float16* bW1r = sW2r + 512 * 1024;                     // 384*1024 f16
  _Float16* bW2r = bW1r + 384 * 1024;                     // 512*1024 f16
  _Float16* aW1r = bW2r + 512 * 1024;                     // 320*1024 f16 (padded)
  _Float16* aW2r = aW1r + 320 * 1024;                     // 512*1024 f16
  size_t needed = (size_t)((char*)(aW2r + 512 * 1024) - (char*)ws);
  if (ws_size < needed) return;

  // 1) gate-interleave + fp16 + chunk-swizzle the six LSTM weight matrices
  auto reorder = [&](const float* W, _Float16* Wr, int Kpad, int D, int Dpad) {
    int total = Kpad * 1024;
    reorder_w_kernel<<<(total + 255) / 256, 256, 0, stream>>>(W, Wr, Kpad, D, Dpad);
  };
  reorder(sW1, sW1r, 384, 128, 128);
  reorder(sW2, sW2r, 512, 512, 512);
  reorder(bW1, bW1r, 384, 128, 128);
  reorder(bW2, bW2r, 512, 512, 512);
  reorder(aW1, aW1r, 320, 50, 64);
  reorder(aW2, aW2r, 512, 512, 512);

  // 2) embeddings (tree + buff fused)
  emb_kernel<<<(2 * kB * kT) / 8, 128, 0, stream>>>(
      twid, tpid, bwid, bpid, W_word, W_pos, emb_W, emb_b, tree_emb, buff_emb);

  // 3) tree composition scan (one block per batch row)
  tree_scan_kernel<<<kB, 128, 0, stream>>>(
      tree_emb, head, depo, relid, leaf, W_rel, rec_W, rec_b, res_g);

  // 4) all three LSTMs, MFMA, 16 rows/block, XCD-pinned (grid 64, 16 idle)
  lstm_mfma_kernel<<<64, 512, 0, stream>>>(
      res_g, buff_emb, W_act, sord, haid, slen, blen, alen,
      sW1r, sb1, sW2r, sb2, bW1r, bb1, bW2r, bb2, aW1r, ab1, aW2r, ab2, hcat);

  // 5) output projection
  final_kernel<<<kB, 128, 0, stream>>>(hcat, fW, fb, (float*)d_out);
}

// Round 4
// 4436.469 us; speedup vs baseline: 2.4261x; 1.9232x over previous
//
#include <hip/hip_runtime.h>
#include <hip/hip_fp16.h>
#include <math.h>

namespace {

constexpr int kB = 256;
constexpr int kT = 128;
constexpr int kFC = 128;
constexpr int kNACT = 82;
constexpr int kWDIM = 300;
constexpr int kPOS = 50;

typedef _Float16 v4h __attribute__((ext_vector_type(4)));
typedef float f32x4 __attribute__((ext_vector_type(4)));

__device__ __forceinline__ float sigf(float x) { return 1.0f / (1.0f + expf(-x)); }

// Device-scope (agent) exchange primitives: write-through / cache-bypassing so
// cross-XCD visibility never depends on L2 writeback fences.
__device__ __forceinline__ v4h ld_agent_v4h(const _Float16* p) {
  unsigned long long raw = __hip_atomic_load((const unsigned long long*)p,
                                             __ATOMIC_RELAXED, __HIP_MEMORY_SCOPE_AGENT);
  return __builtin_bit_cast(v4h, raw);
}
__device__ __forceinline__ void st_agent_h(_Float16* p, _Float16 v) {
  __hip_atomic_store((unsigned short*)p, __builtin_bit_cast(unsigned short, v),
                     __ATOMIC_RELAXED, __HIP_MEMORY_SCOPE_AGENT);
}

// Team barrier: 16 blocks, monotonic counter. Stores are drained by the
// compiler's vmcnt(0) before s_barrier; exchange traffic is agent-scope so no
// L2 writeback is needed for visibility.
__device__ __forceinline__ void team_barrier(int* ctr, int target) {
  __syncthreads();
  if (threadIdx.x == 0) {
    __hip_atomic_fetch_add(ctr, 1, __ATOMIC_RELAXED, __HIP_MEMORY_SCOPE_AGENT);
    while (__hip_atomic_load(ctr, __ATOMIC_RELAXED, __HIP_MEMORY_SCOPE_AGENT) < target)
      __builtin_amdgcn_s_sleep(4);
  }
  __syncthreads();
}

// 4x4 transpose across lane quads: 4 regs x (rows) -> 4 regs x (gates).
__device__ __forceinline__ void quadT(int lane, float& a0, float& a1, float& a2, float& a3) {
  {
    bool odd = lane & 1;
    float s0 = odd ? a0 : a1;
    float s1 = odd ? a2 : a3;
    float r0 = __shfl_xor(s0, 1);
    float r1 = __shfl_xor(s1, 1);
    if (odd) { a0 = r0; a2 = r1; } else { a1 = r0; a3 = r1; }
  }
  {
    bool hi = lane & 2;
    float s0 = hi ? a0 : a2;
    float s1 = hi ? a1 : a3;
    float r0 = __shfl_xor(s0, 2);
    float r1 = __shfl_xor(s1, 2);
    if (hi) { a0 = r0; a1 = r1; } else { a2 = r0; a3 = r1; }
  }
}

// B-frag read (bank-conflict-free: bank = 2*col mod 32) + 2 MFMAs (ntile pair).
__device__ __forceinline__ void mfma_pair(const _Float16* wt, int csA, int kg, v4h a,
                                          f32x4& q0, f32x4& q1) {
  const _Float16* wp = wt + kg * 256 + csA * 4;
  v4h b0 = *(const v4h*)(wp);
  q0 = __builtin_amdgcn_mfma_f32_16x16x16f16(a, b0, q0, 0, 0, 0);
  v4h b1 = *(const v4h*)(wp + 64);
  q1 = __builtin_amdgcn_mfma_f32_16x16x16f16(a, b1, q1, 0, 0, 0);
}

// ---------------------------------------------------------------------------
// Reorder W (K,1024) fp32 -> fp16 team layout:
// Wr[g][kt][kg][cs][ki] with col' = g*64+cs = 4u+gate, k = kt*16+kg*4+ki.
// Rows [D,Dpad) are zero-padded x-section; rows >= Dpad map to h-section.
// ---------------------------------------------------------------------------
__global__ void reorder_team_kernel(const float* __restrict__ W, _Float16* __restrict__ Wr,
                                    int Ktiles, int D, int Dpad, int gstride, int total) {
  int idx = blockIdx.x * 256 + threadIdx.x;
  if (idx >= total) return;
  int per = Ktiles << 10;
  int g = idx / per;
  int rem = idx - g * per;
  int kt = rem >> 10;
  int r2 = rem & 1023;
  int kg = r2 >> 8, cs = (r2 >> 2) & 63, ki = r2 & 3;
  int k = kt * 16 + kg * 4 + ki;
  int src = (k < Dpad) ? ((k < D) ? k : -1) : (D + (k - Dpad));
  int colp = g * 64 + cs;
  int u = colp >> 2, gate = colp & 3;
  _Float16 v = (_Float16)0.f;
  if (src >= 0) v = (_Float16)W[(size_t)src * 1024 + gate * 256 + u];
  Wr[(size_t)g * gstride + rem] = v;
}

// ---------------------------------------------------------------------------
// Embeddings: relu(concat(W_word[wid], W_pos[pid]) @ emb_W + emb_b)
// tree -> f32 (feeds tree_scan), buff -> fp16 (feeds LSTM directly)
// ---------------------------------------------------------------------------
__global__ __launch_bounds__(128) void emb_kernel(
    const int* __restrict__ twid, const int* __restrict__ tpid,
    const int* __restrict__ bwid, const int* __restrict__ bpid,
    const float* __restrict__ W_word, const float* __restrict__ W_pos,
    const float* __restrict__ emb_W, const float* __restrict__ emb_b,
    float* __restrict__ tree_emb, _Float16* __restrict__ buff16) {
  __shared__ float xs[8][352];
  const int tid = threadIdx.x;
  const int pair0 = blockIdx.x * 8;
  const int NTREE = kB * kT;

  for (int p = 0; p < 8; ++p) {
    int P = pair0 + p;
    bool isTree = P < NTREE;
    int idx = isTree ? P : P - NTREE;
    int wid = isTree ? twid[idx] : bwid[idx];
    int pid = isTree ? tpid[idx] : bpid[idx];
    const float* wrow = W_word + (size_t)wid * kWDIM;
    for (int k = tid; k < kWDIM; k += 128) xs[p][k] = wrow[k];
    if (tid < kPOS) xs[p][kWDIM + tid] = W_pos[pid * kPOS + tid];
  }
  __syncthreads();

  float acc[8];
  const float bj = emb_b[tid];
#pragma unroll
  for (int p = 0; p < 8; ++p) acc[p] = bj;

#pragma unroll 10
  for (int k = 0; k < kWDIM + kPOS; ++k) {
    float w = emb_W[k * kFC + tid];
#pragma unroll
    for (int p = 0; p < 8; ++p) acc[p] = fmaf(xs[p][k], w, acc[p]);
  }

  for (int p = 0; p < 8; ++p) {
    int P = pair0 + p;
    bool isTree = P < NTREE;
    int idx = isTree ? P : P - NTREE;
    float v = fmaxf(acc[p], 0.0f);
    if (isTree) tree_emb[(size_t)idx * kFC + tid] = v;
    else buff16[(size_t)idx * kFC + tid] = (_Float16)v;
  }
}

// ---------------------------------------------------------------------------
// Tree composition scan: one block per batch row, res[128][128] in LDS, fp16 out.
// ---------------------------------------------------------------------------
__global__ __launch_bounds__(128) void tree_scan_kernel(
    const float* __restrict__ tree_emb,
    const int* __restrict__ head_ord, const int* __restrict__ dep_ord,
    const int* __restrict__ rel_id, const int* __restrict__ is_leaf,
    const float* __restrict__ W_rel,
    const float* __restrict__ rec_W, const float* __restrict__ rec_b,
    _Float16* __restrict__ res16) {
  __shared__ float res[kT][kFC];
  const int b = blockIdx.x;
  const int j = threadIdx.x;

  res[0][j] = tree_emb[((size_t)b * kT) * kFC + j];
  const float rb = rec_b[j];
  __syncthreads();

  for (int i = 1; i < kT; ++i) {
    const int base = b * kT + i;
    const int leaf = is_leaf[base];
    if (leaf > 0) {
      res[i][j] = tree_emb[(size_t)base * kFC + j];
    } else {
      const int hi = head_ord[base];
      const int di = dep_ord[base];
      const int rid = rel_id[base];
      float acc = rb;
#pragma unroll 8
      for (int k = 0; k < 128; ++k)
        acc = fmaf(res[hi][k], rec_W[k * kFC + j], acc);
#pragma unroll 5
      for (int k = 0; k < 50; ++k)
        acc = fmaf(W_rel[rid * 50 + k], rec_W[(128 + k) * kFC + j], acc);
#pragma unroll 8
      for (int k = 0; k < 128; ++k)
        acc = fmaf(res[di][k], rec_W[(178 + k) * kFC + j], acc);
      res[i][j] = tanhf(acc);
    }
    __syncthreads();
  }

  for (int idx = j; idx < kT * kFC; idx += 128) {
    int t = idx >> 7;
    int jj = idx & 127;
    res16[((size_t)b * kT + t) * kFC + jj] = (_Float16)res[t][jj];
  }
}

// ---------------------------------------------------------------------------
// Persistent-weight team LSTM. Team = 16 blocks, each owns 16 units (64 gate
// cols) with its W-slice resident in LDS. 64 batch rows per team. One barrier
// per phase via layer pipelining: phase p = L1(t=p) + L2(t=p-1). Exchange
// buffers (nh1/h1/h2, parity double-buffered) via agent-scope atomics.
// ---------------------------------------------------------------------------
template <int MODE, int Dt, int K1t, int STEPS>
__device__ void team_lstm(
    int g, int row0, const _Float16* wlds,
    const void* xsrc, const int* __restrict__ order,
    const int* __restrict__ lengths,
    const float* __restrict__ b1, const float* __restrict__ b2,
    _Float16* exch, int* ctr, float* __restrict__ hcat, int hoff) {
  const int tid = threadIdx.x, lane = tid & 63;
  const int wave = tid >> 6, mt = wave >> 1, np = wave & 1;
  const int arow = lane & 15, kg = lane >> 4;
  const int prow = kg * 4 + (lane & 3);
  const int ul = arow >> 2;
  const int csA = np * 32 + arow;

  _Float16* nh1b[2] = {exch, exch + 16384};
  _Float16* h1b[2] = {exch + 32768, exch + 49152};
  _Float16* h2b[2] = {exch + 65536, exch + 81920};

  const int growA = row0 + mt * 16 + arow;
  const int trowA = mt * 16 + arow;
  const int growP = row0 + mt * 16 + prow;
  const int trowP = mt * 16 + prow;
  const int lenP = lengths[growP];

  float bi1[2][4], bi2[2][4];
#pragma unroll
  for (int n = 0; n < 2; ++n) {
    int ug = g * 16 + (2 * np + n) * 4 + ul;
#pragma unroll
    for (int q = 0; q < 4; ++q) {
      bi1[n][q] = b1[q * 256 + ug];
      bi2[n][q] = b2[q * 256 + ug];
    }
  }
  float c1[2] = {0.f, 0.f}, h1st[2] = {0.f, 0.f};
  float c2[2] = {0.f, 0.f}, h2st[2] = {0.f, 0.f};
  const _Float16* w2 = wlds + K1t * 1024;

  for (int p = 0; p <= STEPS; ++p) {
    const int rd = (p + 1) & 1, wr = p & 1;
    const _Float16* h1rd = h1b[rd];
    const _Float16* nh1rd = nh1b[rd];
    const _Float16* h2rd = h2b[rd];
    f32x4 acc1[2], acc2[2];
#pragma unroll
    for (int n = 0; n < 2; ++n) { acc1[n] = 0.f; acc2[n] = 0.f; }

    if (p < STEPS) {
      // ---- layer 1, t = p : x-part ----
      if constexpr (MODE == 2) {
        int aid = order[growA * 256 + p];
        const float* xp = (const float*)xsrc + (size_t)aid * 50;
#pragma unroll
        for (int kt = 0; kt < Dt; ++kt) {
          v4h a;
#pragma unroll
          for (int i = 0; i < 4; ++i) {
            int kk = kt * 16 + kg * 4 + i;
            a[i] = (kk < 50) ? (_Float16)xp[kk] : (_Float16)0.f;
          }
          mfma_pair(wlds + kt * 1024, csA, kg, a, acc1[0], acc1[1]);
        }
      } else {
        const _Float16* x16 = (const _Float16*)xsrc;
        const _Float16* xp;
        if constexpr (MODE == 0) {
          int so = order[growA * 128 + p];
          xp = x16 + ((size_t)growA * 128 + so) * 128;
        } else {
          xp = x16 + ((size_t)growA * 128 + p) * 128;
        }
#pragma unroll
        for (int kt = 0; kt < Dt; ++kt) {
          v4h a = *(const v4h*)(xp + kt * 16 + kg * 4);
          mfma_pair(wlds + kt * 1024, csA, kg, a, acc1[0], acc1[1]);
        }
      }
      // ---- layer 1 h-part (h1 masked, from exchange) ----
#pragma unroll
      for (int kt = Dt; kt < K1t; ++kt) {
        v4h a = ld_agent_v4h(h1rd + trowA * 256 + (kt - Dt) * 16 + kg * 4);
        mfma_pair(wlds + kt * 1024, csA, kg, a, acc1[0], acc1[1]);
      }
    }
    if (p > 0) {
      // ---- layer 2, t = p-1 : [nh1 | h2] ----
#pragma unroll
      for (int kt = 0; kt < 16; ++kt) {
        v4h a = ld_agent_v4h(nh1rd + trowA * 256 + kt * 16 + kg * 4);
        mfma_pair(w2 + kt * 1024, csA, kg, a, acc2[0], acc2[1]);
      }
#pragma unroll
      for (int kt = 16; kt < 32; ++kt) {
        v4h a = ld_agent_v4h(h2rd + trowA * 256 + (kt - 16) * 16 + kg * 4);
        mfma_pair(w2 + kt * 1024, csA, kg, a, acc2[0], acc2[1]);
      }
    }

    // ---- pointwise layer 1 ----
    if (p < STEPS) {
      _Float16* nh1wr = nh1b[wr];
      _Float16* h1wr = h1b[wr];
#pragma unroll
      for (int n = 0; n < 2; ++n) {
        float g0 = acc1[n][0], g1 = acc1[n][1], g2 = acc1[n][2], g3 = acc1[n][3];
        quadT(lane, g0, g1, g2, g3);
        float nc = sigf(g2 + bi1[n][2] + 1.f) * c1[n] + sigf(g0 + bi1[n][0]) * tanhf(g1 + bi1[n][1]);
        float nh = sigf(g3 + bi1[n][3]) * tanhf(nc);
        int ug = g * 16 + (2 * np + n) * 4 + ul;
        st_agent_h(nh1wr + trowP * 256 + ug, (_Float16)nh);  // UNMASKED (layer2 input)
        if (p < lenP) { c1[n] = nc; h1st[n] = nh; }
        st_agent_h(h1wr + trowP * 256 + ug, (_Float16)h1st[n]);  // masked carry
      }
    }
    // ---- pointwise layer 2 (t = p-1) ----
    if (p > 0) {
      _Float16* h2wr = h2b[wr];
#pragma unroll
      for (int n = 0; n < 2; ++n) {
        float g0 = acc2[n][0], g1 = acc2[n][1], g2 = acc2[n][2], g3 = acc2[n][3];
        quadT(lane, g0, g1, g2, g3);
        float nc = sigf(g2 + bi2[n][2] + 1.f) * c2[n] + sigf(g0 + bi2[n][0]) * tanhf(g1 + bi2[n][1]);
        float nh = sigf(g3 + bi2[n][3]) * tanhf(nc);
        int ug = g * 16 + (2 * np + n) * 4 + ul;
        if (p - 1 < lenP) { c2[n] = nc; h2st[n] = nh; }
        st_agent_h(h2wr + trowP * 256 + ug, (_Float16)h2st[n]);  // masked carry
      }
    }

    if (p < STEPS) team_barrier(ctr, 16 * (p + 1));
  }

#pragma unroll
  for (int n = 0; n < 2; ++n) {
    int ug = g * 16 + (2 * np + n) * 4 + ul;
    hcat[(size_t)growP * 768 + hoff + ug] = h2st[n];
  }
}

// 12 teams x 16 blocks = 192 blocks. Team->XCD packing (perf heuristic only;
// correctness is placement-independent via agent-scope exchange):
// teams 0-7 one XCD each, teams 8-11 one XCD pair each.
__global__ __launch_bounds__(512, 2) void lstm_team_kernel(
    const _Float16* res16, const _Float16* buff16, const float* W_act,
    const int* sord, const int* haid,
    const int* slen, const int* blen, const int* alen,
    const _Float16* sWr, const _Float16* bWr, const _Float16* aWr,
    const float* sb1, const float* sb2, const float* bb1, const float* bb2,
    const float* ab1, const float* ab2,
    _Float16* exch, int* ctrs, float* hcat) {
  __shared__ __align__(16) _Float16 wlds[57344];  // 112 KB weight slice

  const int bid = blockIdx.x;
  const int xcd = bid & 7, slot = bid >> 3;
  int tau, g;
  if (slot < 16) { tau = xcd; g = slot; }
  else { tau = 8 + (xcd >> 1); g = (slot - 16) + ((xcd & 1) ? 8 : 0); }

  const _Float16* wsrc;
  int wn;
  if (tau < 4) { wsrc = sWr + (size_t)g * 57344; wn = 57344; }
  else if (tau < 8) { wsrc = bWr + (size_t)g * 57344; wn = 57344; }
  else { wsrc = aWr + (size_t)g * 53248; wn = 53248; }
  for (int i = threadIdx.x * 8; i < wn; i += 512 * 8)
    *(float4*)&wlds[i] = *(const float4*)&wsrc[i];
  __syncthreads();

  _Float16* ex = exch + (size_t)tau * 98304;
  int* ctr = ctrs + tau * 32;

  if (tau < 4) {
    team_lstm<0, 8, 24, 128>(g, tau * 64, wlds, res16, sord, slen, sb1, sb2, ex, ctr, hcat, 0);
  } else if (tau < 8) {
    team_lstm<1, 8, 24, 128>(g, (tau - 4) * 64, wlds, buff16, nullptr, blen, bb1, bb2, ex, ctr, hcat, 256);
  } else {
    team_lstm<2, 4, 20, 256>(g, (tau - 8) * 64, wlds, W_act, haid, alen, ab1, ab2, ex, ctr, hcat, 512);
  }
}

// ---------------------------------------------------------------------------
// Final projection: out[b] = hcat[b] @ fW + fb   (256 x 768) @ (768 x 82)
// ---------------------------------------------------------------------------
__global__ __launch_bounds__(128) void final_kernel(
    const float* __restrict__ hcat, const float* __restrict__ fW,
    const float* __restrict__ fb, float* __restrict__ out) {
  __shared__ float hrow[768];
  const int b = blockIdx.x;
  const int tid = threadIdx.x;
  for (int k = tid; k < 768; k += 128) hrow[k] = hcat[(size_t)b * 768 + k];
  __syncthreads();
  if (tid < kNACT) {
    float acc = fb[tid];
#pragma unroll 8
    for (int k = 0; k < 768; ++k) acc = fmaf(hrow[k], fW[k * kNACT + tid], acc);
    out[(size_t)b * kNACT + tid] = acc;
  }
}

}  // namespace

extern "C" void kernel_launch(void* const* d_in, const int* in_sizes, int n_in,
                              void* d_out, int out_size, void* d_ws, size_t ws_size,
                              hipStream_t stream) {
  const int* twid = (const int*)d_in[0];
  const int* tpid = (const int*)d_in[1];
  const int* bwid = (const int*)d_in[2];
  const int* bpid = (const int*)d_in[3];
  const int* relid = (const int*)d_in[4];
  const int* haid = (const int*)d_in[5];
  const int* head = (const int*)d_in[6];
  const int* depo = (const int*)d_in[7];
  const int* leaf = (const int*)d_in[8];
  const int* sord = (const int*)d_in[9];
  const int* slen = (const int*)d_in[10];
  const int* blen = (const int*)d_in[11];
  const int* alen = (const int*)d_in[12];
  const float* W_word = (const float*)d_in[13];
  const float* W_pos = (const float*)d_in[14];
  const float* W_rel = (const float*)d_in[15];
  const float* W_act = (const float*)d_in[16];
  const float* emb_W = (const float*)d_in[17];
  const float* emb_b = (const float*)d_in[18];
  const float* rec_W = (const float*)d_in[19];
  const float* rec_b = (const float*)d_in[20];
  const float* sW1 = (const float*)d_in[21];
  const float* sb1 = (const float*)d_in[22];
  const float* sW2 = (const float*)d_in[23];
  const float* sb2 = (const float*)d_in[24];
  const float* bW1 = (const float*)d_in[25];
  const float* bb1 = (const float*)d_in[26];
  const float* bW2 = (const float*)d_in[27];
  const float* bb2 = (const float*)d_in[28];
  const float* aW1 = (const float*)d_in[29];
  const float* ab1 = (const float*)d_in[30];
  const float* aW2 = (const float*)d_in[31];
  const float* ab2 = (const float*)d_in[32];
  const float* fW = (const float*)d_in[33];
  const float* fb = (const float*)d_in[34];

  // ---- workspace carve-up ----
  char* w = (char*)d_ws;
  float* tree_emb = (float*)w;            w += (size_t)kB * kT * kFC * 4;   // 16.78 MB
  _Float16* buff16 = (_Float16*)w;        w += (size_t)kB * kT * kFC * 2;   // 8.39 MB
  _Float16* res16 = (_Float16*)w;         w += (size_t)kB * kT * kFC * 2;   // 8.39 MB
  float* hcat = (float*)w;                w += (size_t)kB * 768 * 4;        // 0.79 MB
  _Float16* sWr = (_Float16*)w;           w += (size_t)57344 * 16 * 2;      // 1.84 MB
  _Float16* bWr = (_Float16*)w;           w += (size_t)57344 * 16 * 2;      // 1.84 MB
  _Float16* aWr = (_Float16*)w;           w += (size_t)53248 * 16 * 2;      // 1.70 MB
  _Float16* exch = (_Float16*)w;          w += (size_t)12 * 98304 * 2;      // 2.36 MB
  int* ctrs = (int*)w;                    w += (size_t)12 * 32 * 4;
  size_t needed = (size_t)(w - (char*)d_ws);
  if (ws_size < needed) return;

  // 0) zero exchange buffers + barrier counters (every launch; deterministic)
  hipMemsetAsync(exch, 0, (size_t)12 * 98304 * 2 + (size_t)12 * 32 * 4, stream);

  // 1) team-layout fp16 weight reorder
  auto reorder = [&](const float* W, _Float16* Wr, int Kt, int D, int Dpad, int gstride) {
    int total = 16 * Kt * 1024;
    reorder_team_kernel<<<(total + 255) / 256, 256, 0, stream>>>(W, Wr, Kt, D, Dpad, gstride, total);
  };
  reorder(sW1, sWr, 24, 128, 128, 57344);
  reorder(sW2, sWr + 24 * 1024, 32, 512, 512, 57344);
  reorder(bW1, bWr, 24, 128, 128, 57344);
  reorder(bW2, bWr + 24 * 1024, 32, 512, 512, 57344);
  reorder(aW1, aWr, 20, 50, 64, 53248);
  reorder(aW2, aWr + 20 * 1024, 32, 512, 512, 53248);

  // 2) embeddings (tree f32, buff fp16)
  emb_kernel<<<(2 * kB * kT) / 8, 128, 0, stream>>>(
      twid, tpid, bwid, bpid, W_word, W_pos, emb_W, emb_b, tree_emb, buff16);

  // 3) tree composition scan -> fp16
  tree_scan_kernel<<<kB, 128, 0, stream>>>(
      tree_emb, head, depo, relid, leaf, W_rel, rec_W, rec_b, res16);

  // 4) persistent-weight team LSTMs (cooperative: residency guarantee)
  {
    const _Float16* a0 = res16; const _Float16* a1 = buff16; const float* a2 = W_act;
    const int* a3 = sord; const int* a4 = haid;
    const int* a5 = slen; const int* a6 = blen; const int* a7 = alen;
    const _Float16* a8 = sWr; const _Float16* a9 = bWr; const _Float16* a10 = aWr;
    const float* a11 = sb1; const float* a12 = sb2; const float* a13 = bb1; const float* a14 = bb2;
    const float* a15 = ab1; const float* a16 = ab2;
    _Float16* a17 = exch; int* a18 = ctrs; float* a19 = hcat;
    void* kargs[] = {&a0, &a1, &a2, &a3, &a4, &a5, &a6, &a7, &a8, &a9, &a10,
                     &a11, &a12, &a13, &a14, &a15, &a16, &a17, &a18, &a19};
    hipLaunchCooperativeKernel((const void*)lstm_team_kernel, dim3(192), dim3(512),
                               kargs, 0, stream);
  }

  // 5) output projection
  final_kernel<<<kB, 128, 0, stream>>>(hcat, fW, fb, (float*)d_out);
}